// Round 14
// baseline (4616.774 us; speedup 1.0000x reference)
//
#include <hip/hip_runtime.h>
#include <hip/hip_bf16.h>

#define VOCAB 10000
#define HID   1024
#define OUTN  10000
#define BATCH 32
#define SEQT  256
#define NPAD  10112   // 79*128

typedef short s16x8 __attribute__((ext_vector_type(8)));
typedef float f32x4 __attribute__((ext_vector_type(4)));
typedef unsigned u32x2 __attribute__((ext_vector_type(2)));

// NOTE gfx950 operand order: offset:imm must precede sc0/sc1 cache flags.
#define ALOAD16_SC(dst, base, off)                                                   \
  asm volatile("global_load_dwordx4 %0, %1, off offset:%2 sc0 sc1"                   \
               : "=v"(dst) : "v"(base), "n"(off) : "memory")

__device__ __forceinline__ unsigned bfbits(float f) {
  __hip_bfloat16 h = __float2bfloat16(f);
  return (unsigned)*reinterpret_cast<unsigned short*>(&h);
}

// ---------------------------------------------------------------- transpose+cast
__global__ __launch_bounds__(256) void transpose_cast(
    const float* __restrict__ src, __hip_bfloat16* __restrict__ dst,
    int K, int N, int Npad) {
  __shared__ float tile[32][33];
  const int n0 = blockIdx.x * 32, k0 = blockIdx.y * 32;
  const int tx = threadIdx.x & 31, ty = threadIdx.x >> 5;  // 32 x 8
#pragma unroll
  for (int yy = 0; yy < 32; yy += 8) {
    const int k = k0 + ty + yy, n = n0 + tx;
    tile[ty + yy][tx] = (k < K && n < N) ? src[k * N + n] : 0.f;
  }
  __syncthreads();
#pragma unroll
  for (int yy = 0; yy < 32; yy += 8) {
    const int n = n0 + ty + yy, k = k0 + tx;
    if (n < Npad && k < K) dst[(size_t)n * K + k] = __float2bfloat16(tile[tx][ty + yy]);
  }
}

// cast state + zero the flag region every launch (replay-safe)
__global__ __launch_bounds__(256) void cast_state(
    const float* __restrict__ s, __hip_bfloat16* __restrict__ d, int n,
    unsigned* __restrict__ zero_base, int zero_n) {
  const int i = blockIdx.x * 256 + threadIdx.x;
  if (i < n) d[i] = __float2bfloat16(s[i]);
  if (i < zero_n) zero_base[i] = 0u;
}

// ---------------------------------------------------------------- fused persistent kernel
// blockIdx < 32 : PRODUCER — R11 recurrence verbatim (passed, absmax 2.44e-4);
//   the only additions are a mirror-flag store (separate cachelines, polled by
//   consumers so their traffic never touches the producers' spin lines) and a
//   final flag=256 after the loop.
// blockIdx >= 32: CONSUMER — one 128-col tile of Y per WG; for tt=1..256 wait
//   mirror flags >= tt (s_sleep backoff), sc0sc1-load H slot tt, MFMA against
//   L2-resident W_hqT, store Y rows (tt-1)*32.. with b_q fused.
// Deadlock-free: consumers wait only on producers; producers (32 WGs, always
// co-resident) wait only on each other; flags are monotone and reach 256
// before producers exit, so late-scheduled consumers just stream through.
__global__ __launch_bounds__(256, 1) void rnn_persist(
    __hip_bfloat16* __restrict__ Hbf,          // 257 slots of [32][1024] bf16
    const int* __restrict__ ids,               // [BATCH][SEQT]
    const float* __restrict__ W_xh,            // [VOCAB][HID] f32
    const __hip_bfloat16* __restrict__ WhhT,   // [HID][HID] bf16, [n][k]
    const float* __restrict__ b_h,
    float* __restrict__ Hfin,                  // [32][1024] f32 (tail of d_out)
    unsigned* __restrict__ flags,              // 32 x 32-dword stride (producers poll)
    unsigned* __restrict__ mirror,             // 32 x 32-dword stride (consumers poll)
    const __hip_bfloat16* __restrict__ WhqT,   // [NPAD][HID] bf16
    const float* __restrict__ b_q,
    float* __restrict__ Y) {                   // [8192][10000] f32
  // producer W-slice cache: [32 cols][1024 k], 16B chunks XOR-swizzled
  __shared__ __align__(16) __hip_bfloat16 whh[32 * HID];   // 64 KB

  const int wave = threadIdx.x >> 6;
  const int lane = threadIdx.x & 63;
  const int wm = wave >> 1, wn = wave & 1;
  const int l16 = lane & 15;
  const int g   = lane >> 4;                   // 0..3

  if (blockIdx.x < 32) {
    // ================= PRODUCER (R11 verbatim) =================
    const int wg = blockIdx.x;
    const int r0 = wm * 16;
    const int c0 = wg * 32 + wn * 16;

    for (int ci = threadIdx.x; ci < 32 * (HID / 8); ci += 256) {
      const int col = ci >> 7;
      const int c16 = ci & 127;
      const s16x8 v = *reinterpret_cast<const s16x8*>(
          WhhT + (size_t)(wg * 32 + col) * HID + c16 * 8);
      const int sw = (c16 & ~7) | ((c16 & 7) ^ (col & 7));
      *reinterpret_cast<s16x8*>(reinterpret_cast<char*>(whh) + col * 2048 + sw * 16) = v;
    }

    const int orow = r0 + l16;
    const int oc   = c0 + g * 4;
    const f32x4 bh4 = *reinterpret_cast<const f32x4*>(b_h + oc);

    f32x4 wxh4 = *reinterpret_cast<const f32x4*>(
        W_xh + (size_t)ids[orow * SEQT + 0] * HID + oc);

    __syncthreads();   // whh staged

    const int aOff = (r0 + l16) * HID + g * 8;
    const char* myB = reinterpret_cast<const char*>(whh) + (wn * 16 + l16) * 2048;
    const int xorv = l16 & 7;
    const int offE = (g ^ xorv) * 16;
    const int offO = ((g + 4) ^ xorv) * 16;

    for (int t = 0; t < SEQT; ++t) {
      const __hip_bfloat16* aBase = Hbf + (size_t)t * (BATCH * HID) + aOff;
      __hip_bfloat16* Hnext = Hbf + (size_t)(t + 1) * (BATCH * HID);

      s16x8 areg[32];
#pragma unroll
      for (int kk = 0; kk < 32; ++kk) ALOAD16_SC(areg[kk], aBase, kk * 64);
      asm volatile("s_waitcnt vmcnt(0)" ::: "memory");
      __builtin_amdgcn_sched_barrier(0);

      f32x4 acc0 = {0.f, 0.f, 0.f, 0.f}, acc1 = {0.f, 0.f, 0.f, 0.f};
#pragma unroll
      for (int kk = 0; kk < 32; kk += 2) {
        const s16x8 b0 = *reinterpret_cast<const s16x8*>(myB + (kk >> 1) * 128 + offE);
        const s16x8 b1 = *reinterpret_cast<const s16x8*>(myB + (kk >> 1) * 128 + offO);
        acc0 = __builtin_amdgcn_mfma_f32_16x16x32_bf16(b0, areg[kk],     acc0, 0, 0, 0);
        acc1 = __builtin_amdgcn_mfma_f32_16x16x32_bf16(b1, areg[kk + 1], acc1, 0, 0, 0);
      }

      float x[4];
#pragma unroll
      for (int jj = 0; jj < 4; ++jj) {
        const float s = acc0[jj] + acc1[jj] + wxh4[jj] + bh4[jj];
        const float e = __expf(2.f * s);           // tanh = 1 - 2/(e^{2x}+1)
        x[jj] = 1.f - 2.f / (e + 1.f);
      }
      u32x2 pk;
      pk[0] = bfbits(x[0]) | (bfbits(x[1]) << 16);
      pk[1] = bfbits(x[2]) | (bfbits(x[3]) << 16);
      asm volatile("global_store_dwordx2 %0, %1, off sc0 sc1"
                   :: "v"(Hnext + orow * HID + oc), "v"(pk) : "memory");
      if (t == SEQT - 1)
        *reinterpret_cast<f32x4*>(Hfin + orow * HID + oc) = (f32x4){x[0], x[1], x[2], x[3]};

      if (t + 1 < SEQT) {
        asm volatile("s_waitcnt vmcnt(0)" ::: "memory");
        __syncthreads();
        if (threadIdx.x == 0) {
          atomicExch(flags + wg * 32, (unsigned)(t + 1));
          atomicExch(mirror + wg * 32, (unsigned)(t + 1));   // consumers' copy
        }

        wxh4 = *reinterpret_cast<const f32x4*>(
            W_xh + (size_t)ids[orow * SEQT + (t + 1)] * HID + oc);

        const unsigned* myflag = flags + (lane & 31) * 32;
        const unsigned target = (unsigned)(t + 1);
        unsigned f;
        do {
          asm volatile("global_load_dword %0, %1, off sc0 sc1\n\t"
                       "s_waitcnt vmcnt(0)"
                       : "=v"(f) : "v"(myflag) : "memory");
        } while (__all((int)(f >= target)) == 0);
        __builtin_amdgcn_sched_barrier(0);
      }
    }
    // final release: H slot 256 drained -> flag 256 (consumers' last wait)
    asm volatile("s_waitcnt vmcnt(0)" ::: "memory");
    __syncthreads();
    if (threadIdx.x == 0) {
      atomicExch(flags + blockIdx.x * 32, (unsigned)SEQT);
      atomicExch(mirror + blockIdx.x * 32, (unsigned)SEQT);
    }
    return;
  }

  // ================= CONSUMER =================
  const int cw = blockIdx.x - 32;              // 0..78, owns cols [cw*128, +128)
  const int yr0 = wm * 16 + g * 4;             // wave's batch-row base + reg row

  // B pointers: 4 col-frags (wn*64 + n*16), loop-invariant
  const __hip_bfloat16* wq[4];
  float bq[4];
  int ocol[4];
#pragma unroll
  for (int n = 0; n < 4; ++n) {
    ocol[n] = cw * 128 + wn * 64 + n * 16 + l16;
    wq[n] = WhqT + (size_t)ocol[n] * HID + g * 8;
    bq[n] = (ocol[n] < OUTN) ? b_q[ocol[n]] : 0.f;
  }
  const int aOff = (wm * 16 + l16) * HID + g * 8;

  for (int tt = 1; tt <= SEQT; ++tt) {
    // wait mirror flags >= tt (lane l watches mirror[l&31]); backoff spin
    {
      const unsigned* myflag = mirror + (lane & 31) * 32;
      unsigned f;
      while (true) {
        asm volatile("global_load_dword %0, %1, off sc0 sc1\n\t"
                     "s_waitcnt vmcnt(0)"
                     : "=v"(f) : "v"(myflag) : "memory");
        if (__all((int)(f >= (unsigned)tt))) break;
        __builtin_amdgcn_s_sleep(8);
      }
      __builtin_amdgcn_sched_barrier(0);
    }

    // load H slot tt fragments (same acquire pattern as producers)
    s16x8 areg[32];
    const __hip_bfloat16* aBase = Hbf + (size_t)tt * (BATCH * HID) + aOff;
#pragma unroll
    for (int kk = 0; kk < 32; ++kk) ALOAD16_SC(areg[kk], aBase, kk * 64);
    asm volatile("s_waitcnt vmcnt(0)" ::: "memory");
    __builtin_amdgcn_sched_barrier(0);

    // 4 output frags: 16 rows x 64 cols per wave
    f32x4 acc[4] = {{0.f,0.f,0.f,0.f},{0.f,0.f,0.f,0.f},{0.f,0.f,0.f,0.f},{0.f,0.f,0.f,0.f}};
#pragma unroll
    for (int kk = 0; kk < 32; ++kk) {
#pragma unroll
      for (int n = 0; n < 4; ++n) {
        const s16x8 w = *reinterpret_cast<const s16x8*>(wq[n] + kk * 32);
        acc[n] = __builtin_amdgcn_mfma_f32_16x16x32_bf16(areg[kk], w, acc[n], 0, 0, 0);
      }
    }

    // epilogue: Y rows (tt-1)*32 + yr0 + j, col ocol[n]
    const size_t yrBase = (size_t)(tt - 1) * 32 + yr0;
#pragma unroll
    for (int n = 0; n < 4; ++n) {
      if (ocol[n] < OUTN) {
#pragma unroll
        for (int j = 0; j < 4; ++j)
          Y[(yrBase + j) * OUTN + ocol[n]] = acc[n][j] + bq[n];
      }
    }
  }
}

// ---------------------------------------------------------------- launch
extern "C" void kernel_launch(void* const* d_in, const int* in_sizes, int n_in,
                              void* d_out, int out_size, void* d_ws, size_t ws_size,
                              hipStream_t stream) {
  const int*   inputs = (const int*)d_in[0];
  const float* state  = (const float*)d_in[1];
  const float* W_xh   = (const float*)d_in[2];
  const float* W_hh   = (const float*)d_in[3];
  const float* b_h    = (const float*)d_in[4];
  const float* W_hq   = (const float*)d_in[5];
  const float* b_q    = (const float*)d_in[6];

  float* Y    = (float*)d_out;                        // [8192][10000]
  float* Hfin = Y + (size_t)SEQT * BATCH * OUTN;      // [32][1024]

  char* ws = (char*)d_ws;
  __hip_bfloat16* Hbf  = (__hip_bfloat16*)ws;                     // 16,842,752 B
  __hip_bfloat16* WhhT = (__hip_bfloat16*)(ws + 16842752);        //  2,097,152 B
  __hip_bfloat16* WhqT = (__hip_bfloat16*)(ws + 18939904);        // 20,709,376 B
  unsigned* flags      = (unsigned*)(ws + 39649280);              //      4,096 B
  unsigned* mirror     = (unsigned*)(ws + 39653376);              //      4,096 B
  const int zero_n = 8192 / 4;   // flags+mirror zeroed every launch

  transpose_cast<<<dim3(32, 32), 256, 0, stream>>>(W_hh, WhhT, HID, HID, HID);
  transpose_cast<<<dim3(NPAD / 32, 32), 256, 0, stream>>>(W_hq, WhqT, HID, OUTN, NPAD);
  cast_state<<<dim3(128), 256, 0, stream>>>(state, Hbf, BATCH * HID, flags, zero_n);

  rnn_persist<<<dim3(32 + NPAD / 128), dim3(256), 0, stream>>>(
      Hbf, inputs, W_xh, WhhT, b_h, Hfin, flags, mirror, WhqT, b_q, Y);
}

// Round 15
// 1560.005 us; speedup vs baseline: 2.9595x; 2.9595x over previous
//
#include <hip/hip_runtime.h>
#include <hip/hip_bf16.h>

#define VOCAB 10000
#define HID   1024
#define OUTN  10000
#define BATCH 32
#define SEQT  256
#define NPAD  10112   // 79*128

typedef short s16x8 __attribute__((ext_vector_type(8)));
typedef float f32x4 __attribute__((ext_vector_type(4)));
typedef unsigned u32x2 __attribute__((ext_vector_type(2)));

#define GLOAD_LDS16(gptr, lptr)                                                      \
  __builtin_amdgcn_global_load_lds((__attribute__((address_space(1))) void*)(gptr),  \
                                   (__attribute__((address_space(3))) void*)(lptr),  \
                                   16, 0, 0)

// NOTE gfx950 operand order: offset:imm must precede sc0/sc1 cache flags.
#define ALOAD16_SC(dst, base, off)                                                   \
  asm volatile("global_load_dwordx4 %0, %1, off offset:%2 sc0 sc1"                   \
               : "=v"(dst) : "v"(base), "n"(off) : "memory")

__device__ __forceinline__ unsigned bfbits(float f) {
  __hip_bfloat16 h = __float2bfloat16(f);
  return (unsigned)*reinterpret_cast<unsigned short*>(&h);
}

// ---------------------------------------------------------------- transpose+cast
__global__ __launch_bounds__(256) void transpose_cast(
    const float* __restrict__ src, __hip_bfloat16* __restrict__ dst,
    int K, int N, int Npad) {
  __shared__ float tile[32][33];
  const int n0 = blockIdx.x * 32, k0 = blockIdx.y * 32;
  const int tx = threadIdx.x & 31, ty = threadIdx.x >> 5;  // 32 x 8
#pragma unroll
  for (int yy = 0; yy < 32; yy += 8) {
    const int k = k0 + ty + yy, n = n0 + tx;
    tile[ty + yy][tx] = (k < K && n < N) ? src[k * N + n] : 0.f;
  }
  __syncthreads();
#pragma unroll
  for (int yy = 0; yy < 32; yy += 8) {
    const int n = n0 + ty + yy, k = k0 + tx;
    if (n < Npad && k < K) dst[(size_t)n * K + k] = __float2bfloat16(tile[tx][ty + yy]);
  }
}

// cast state + zero the flag region every launch (replay-safe)
__global__ __launch_bounds__(256) void cast_state(
    const float* __restrict__ s, __hip_bfloat16* __restrict__ d, int n,
    unsigned* __restrict__ zero_base, int zero_n) {
  const int i = blockIdx.x * 256 + threadIdx.x;
  if (i < n) d[i] = __float2bfloat16(s[i]);
  if (i < zero_n) zero_base[i] = 0u;
}

// ---------------------------------------------------------------- fused persistent kernel
// blockIdx < 32 : PRODUCER — R11 recurrence verbatim + mirror flag + final 256.
// blockIdx >= 32: CONSUMER — owns one 128-col slice of Y; processes it as 64
//   sequential 128x128 m-tiles (4 time-steps each) using the PROVEN gemm_out
//   tile structure (global_load_lds staging, XOR swizzle). Gate: m-tile mt
//   needs H slots mt*4+1..mt*4+4 => wait mirror >= (mt+1)*4.
//   Coherence: every Hbf slot is written once (sc0sc1 -> IC) and never read
//   by anyone before its flag is set => no L2 can hold a stale copy within a
//   dispatch (dispatch-boundary acquire covers replays) => consumers may use
//   normal cached loads; the XCD's consumers then SHARE the H tile via L2.
// Deadlock-free: consumers wait only on producer flags (monotone, reach 256
// before producers exit); producers (32 WGs, co-resident) wait on each other.
__global__ __launch_bounds__(256, 1) void rnn_persist(
    __hip_bfloat16* __restrict__ Hbf,          // 257 slots of [32][1024] bf16
    const int* __restrict__ ids,               // [BATCH][SEQT]
    const float* __restrict__ W_xh,            // [VOCAB][HID] f32
    const __hip_bfloat16* __restrict__ WhhT,   // [HID][HID] bf16, [n][k]
    const float* __restrict__ b_h,
    float* __restrict__ Hfin,                  // [32][1024] f32 (tail of d_out)
    unsigned* __restrict__ flags,              // 32 x 32-dword stride (producers poll)
    unsigned* __restrict__ mirror,             // 32 x 32-dword stride (consumers poll)
    const __hip_bfloat16* __restrict__ WhqT,   // [NPAD][HID] bf16
    const float* __restrict__ b_q,
    float* __restrict__ Y) {                   // [8192][10000] f32
  // 64 KB shared: producer uses it as whh[32][1024]; consumer as As|Bs tiles
  __shared__ __align__(16) __hip_bfloat16 smem[32 * HID];

  const int wave = threadIdx.x >> 6;
  const int lane = threadIdx.x & 63;
  const int wm = wave >> 1, wn = wave & 1;
  const int l16 = lane & 15;
  const int g   = lane >> 4;                   // 0..3

  if (blockIdx.x < 32) {
    // ================= PRODUCER (R11 verbatim) =================
    __hip_bfloat16* whh = smem;
    const int wg = blockIdx.x;
    const int r0 = wm * 16;
    const int c0 = wg * 32 + wn * 16;

    for (int ci = threadIdx.x; ci < 32 * (HID / 8); ci += 256) {
      const int col = ci >> 7;
      const int c16 = ci & 127;
      const s16x8 v = *reinterpret_cast<const s16x8*>(
          WhhT + (size_t)(wg * 32 + col) * HID + c16 * 8);
      const int sw = (c16 & ~7) | ((c16 & 7) ^ (col & 7));
      *reinterpret_cast<s16x8*>(reinterpret_cast<char*>(whh) + col * 2048 + sw * 16) = v;
    }

    const int orow = r0 + l16;
    const int oc   = c0 + g * 4;
    const f32x4 bh4 = *reinterpret_cast<const f32x4*>(b_h + oc);

    f32x4 wxh4 = *reinterpret_cast<const f32x4*>(
        W_xh + (size_t)ids[orow * SEQT + 0] * HID + oc);

    __syncthreads();   // whh staged

    const int aOff = (r0 + l16) * HID + g * 8;
    const char* myB = reinterpret_cast<const char*>(whh) + (wn * 16 + l16) * 2048;
    const int xorv = l16 & 7;
    const int offE = (g ^ xorv) * 16;
    const int offO = ((g + 4) ^ xorv) * 16;

    for (int t = 0; t < SEQT; ++t) {
      const __hip_bfloat16* aBase = Hbf + (size_t)t * (BATCH * HID) + aOff;
      __hip_bfloat16* Hnext = Hbf + (size_t)(t + 1) * (BATCH * HID);

      s16x8 areg[32];
#pragma unroll
      for (int kk = 0; kk < 32; ++kk) ALOAD16_SC(areg[kk], aBase, kk * 64);
      asm volatile("s_waitcnt vmcnt(0)" ::: "memory");
      __builtin_amdgcn_sched_barrier(0);

      f32x4 acc0 = {0.f, 0.f, 0.f, 0.f}, acc1 = {0.f, 0.f, 0.f, 0.f};
#pragma unroll
      for (int kk = 0; kk < 32; kk += 2) {
        const s16x8 b0 = *reinterpret_cast<const s16x8*>(myB + (kk >> 1) * 128 + offE);
        const s16x8 b1 = *reinterpret_cast<const s16x8*>(myB + (kk >> 1) * 128 + offO);
        acc0 = __builtin_amdgcn_mfma_f32_16x16x32_bf16(b0, areg[kk],     acc0, 0, 0, 0);
        acc1 = __builtin_amdgcn_mfma_f32_16x16x32_bf16(b1, areg[kk + 1], acc1, 0, 0, 0);
      }

      float x[4];
#pragma unroll
      for (int jj = 0; jj < 4; ++jj) {
        const float s = acc0[jj] + acc1[jj] + wxh4[jj] + bh4[jj];
        const float e = __expf(2.f * s);           // tanh = 1 - 2/(e^{2x}+1)
        x[jj] = 1.f - 2.f / (e + 1.f);
      }
      u32x2 pk;
      pk[0] = bfbits(x[0]) | (bfbits(x[1]) << 16);
      pk[1] = bfbits(x[2]) | (bfbits(x[3]) << 16);
      asm volatile("global_store_dwordx2 %0, %1, off sc0 sc1"
                   :: "v"(Hnext + orow * HID + oc), "v"(pk) : "memory");
      if (t == SEQT - 1)
        *reinterpret_cast<f32x4*>(Hfin + orow * HID + oc) = (f32x4){x[0], x[1], x[2], x[3]};

      if (t + 1 < SEQT) {
        asm volatile("s_waitcnt vmcnt(0)" ::: "memory");
        __syncthreads();
        if (threadIdx.x == 0) {
          atomicExch(flags + wg * 32, (unsigned)(t + 1));
          atomicExch(mirror + wg * 32, (unsigned)(t + 1));   // consumers' copy
        }

        wxh4 = *reinterpret_cast<const f32x4*>(
            W_xh + (size_t)ids[orow * SEQT + (t + 1)] * HID + oc);

        const unsigned* myflag = flags + (lane & 31) * 32;
        const unsigned target = (unsigned)(t + 1);
        unsigned f;
        do {
          asm volatile("global_load_dword %0, %1, off sc0 sc1\n\t"
                       "s_waitcnt vmcnt(0)"
                       : "=v"(f) : "v"(myflag) : "memory");
        } while (__all((int)(f >= target)) == 0);
        __builtin_amdgcn_sched_barrier(0);
      }
    }
    // final release: H slot 256 drained -> flag 256 (consumers' last gate)
    asm volatile("s_waitcnt vmcnt(0)" ::: "memory");
    __syncthreads();
    if (threadIdx.x == 0) {
      atomicExch(flags + blockIdx.x * 32, (unsigned)SEQT);
      atomicExch(mirror + blockIdx.x * 32, (unsigned)SEQT);
    }
    return;
  }

  // ================= CONSUMER (gemm_out tile structure) =================
  __hip_bfloat16* As = smem;                   // [128*64]
  __hip_bfloat16* Bs = smem + 128 * 64;        // [128*64]
  const int bx = blockIdx.x - 32;              // n-tile 0..78
  const __hip_bfloat16* A = Hbf + BATCH * HID; // slot-1 base: row r = t*32+b
  const size_t bRow0 = (size_t)bx * 128;

  for (int mt = 0; mt < 64; ++mt) {
    // gate: need H slots mt*4+1 .. mt*4+4  =>  mirror >= (mt+1)*4
    {
      const unsigned need = (unsigned)((mt + 1) * 4);
      const unsigned* myflag = mirror + (lane & 31) * 32;
      unsigned f;
      while (true) {
        asm volatile("global_load_dword %0, %1, off sc0 sc1\n\t"
                     "s_waitcnt vmcnt(0)"
                     : "=v"(f) : "v"(myflag) : "memory");
        if (__all((int)(f >= need))) break;
        __builtin_amdgcn_s_sleep(8);
      }
      __builtin_amdgcn_sched_barrier(0);
    }

    const size_t aRow0 = (size_t)mt * 128;
    f32x4 acc[4][4];
#pragma unroll
    for (int m = 0; m < 4; ++m)
#pragma unroll
      for (int n = 0; n < 4; ++n) acc[m][n] = (f32x4){0.f, 0.f, 0.f, 0.f};

    for (int kt = 0; kt < HID / 64; ++kt) {
      __syncthreads();
#pragma unroll
      for (int q = 0; q < 4; ++q) {
        const int ci = q * 256 + wave * 64 + lane;   // chunk 0..1023 (16B each)
        const int r  = ci >> 3;                      // tile row 0..127
        const int gc = (ci & 7) ^ (r & 7);           // swizzled source chunk
        const __hip_bfloat16* ga = A    + (aRow0 + r) * HID + kt * 64 + gc * 8;
        const __hip_bfloat16* gb = WhqT + (bRow0 + r) * HID + kt * 64 + gc * 8;
        GLOAD_LDS16(ga, &As[(q * 256 + wave * 64) * 8]);
        GLOAD_LDS16(gb, &Bs[(q * 256 + wave * 64) * 8]);
      }
      __syncthreads();

      s16x8 af[2][4], bf[2][4];
#pragma unroll
      for (int kc = 0; kc < 2; ++kc) {
        const int cc = kc * 4 + g;
#pragma unroll
        for (int m = 0; m < 4; ++m) {
          const int rowA = wm * 64 + m * 16 + l16;
          af[kc][m] = *reinterpret_cast<const s16x8*>(&As[rowA * 64 + ((cc ^ (rowA & 7)) * 8)]);
        }
#pragma unroll
        for (int n = 0; n < 4; ++n) {
          const int rowB = wn * 64 + n * 16 + l16;
          bf[kc][n] = *reinterpret_cast<const s16x8*>(&Bs[rowB * 64 + ((cc ^ (rowB & 7)) * 8)]);
        }
      }
#pragma unroll
      for (int kc = 0; kc < 2; ++kc)
#pragma unroll
        for (int m = 0; m < 4; ++m)
#pragma unroll
          for (int n = 0; n < 4; ++n)
            acc[m][n] = __builtin_amdgcn_mfma_f32_16x16x32_bf16(af[kc][m], bf[kc][n], acc[m][n], 0, 0, 0);
    }

    const int crow0 = (int)aRow0 + wm * 64 + g * 4;
    const int ccol0 = bx * 128 + wn * 64 + l16;
#pragma unroll
    for (int n = 0; n < 4; ++n) {
      const int ccol = ccol0 + n * 16;
      if (ccol < OUTN) {
        const float bq = b_q[ccol];
#pragma unroll
        for (int m = 0; m < 4; ++m) {
          const int crow = crow0 + m * 16;
#pragma unroll
          for (int j = 0; j < 4; ++j)
            Y[(size_t)(crow + j) * OUTN + ccol] = acc[m][n][j] + bq;
        }
      }
    }
  }
}

// ---------------------------------------------------------------- launch
extern "C" void kernel_launch(void* const* d_in, const int* in_sizes, int n_in,
                              void* d_out, int out_size, void* d_ws, size_t ws_size,
                              hipStream_t stream) {
  const int*   inputs = (const int*)d_in[0];
  const float* state  = (const float*)d_in[1];
  const float* W_xh   = (const float*)d_in[2];
  const float* W_hh   = (const float*)d_in[3];
  const float* b_h    = (const float*)d_in[4];
  const float* W_hq   = (const float*)d_in[5];
  const float* b_q    = (const float*)d_in[6];

  float* Y    = (float*)d_out;                        // [8192][10000]
  float* Hfin = Y + (size_t)SEQT * BATCH * OUTN;      // [32][1024]

  char* ws = (char*)d_ws;
  __hip_bfloat16* Hbf  = (__hip_bfloat16*)ws;                     // 16,842,752 B
  __hip_bfloat16* WhhT = (__hip_bfloat16*)(ws + 16842752);        //  2,097,152 B
  __hip_bfloat16* WhqT = (__hip_bfloat16*)(ws + 18939904);        // 20,709,376 B
  unsigned* flags      = (unsigned*)(ws + 39649280);              //      4,096 B
  unsigned* mirror     = (unsigned*)(ws + 39653376);              //      4,096 B
  const int zero_n = 8192 / 4;   // flags+mirror zeroed every launch

  transpose_cast<<<dim3(32, 32), 256, 0, stream>>>(W_hh, WhhT, HID, HID, HID);
  transpose_cast<<<dim3(NPAD / 32, 32), 256, 0, stream>>>(W_hq, WhqT, HID, OUTN, NPAD);
  cast_state<<<dim3(128), 256, 0, stream>>>(state, Hbf, BATCH * HID, flags, zero_n);

  rnn_persist<<<dim3(32 + NPAD / 128), dim3(256), 0, stream>>>(
      Hbf, inputs, W_xh, WhhT, b_h, Hfin, flags, mirror, WhqT, b_q, Y);
}